// Round 1
// baseline (39183.246 us; speedup 1.0000x reference)
//
#include <hip/hip_runtime.h>
#include <hip/hip_cooperative_groups.h>

namespace cg = cooperative_groups;

// Problem constants (fixed by setup_inputs / reference)
constexpr int   NROWS   = 131072;
constexpr int   KCOLS   = 512;
constexpr int   KP1     = 513;   // + dummy column
constexpr int   KPAD    = 516;   // pad b-buffers to 16B multiple
constexpr float PA      = 1.0f / 131072.0f;   // 2^-17, exact
constexpr float PB_REAL = 0.5f / 512.0f;      // exact
constexpr float PB_DUM  = 0.5f;
constexpr float FI      = (float)(1.0 / 1.1); // GAMMA/(GAMMA+EPSILON)
constexpr float STOPERR = 1e-6f;
constexpr int   MAXIT   = 1000;
constexpr float LOG2E   = 1.4426950408889634f;
constexpr float CQ      = 10.0f * LOG2E;      // (1/EPSILON)*log2(e)
constexpr float LN2     = 0.6931471805599453f;

// Cooperative kernel config: 256 blocks x 1024 threads = 1 block/CU, 16 waves/CU
constexpr int BLOCKS  = 256;
constexpr int THREADS = 1024;
constexpr int WPB     = THREADS / 64;     // 16 waves per block
constexpr int NWAVES  = BLOCKS * WPB;     // 4096 waves

// Workspace layout (in floats). Total ~395k floats = 1.58 MB.
constexpr size_t OFF_LSE = 0;                        // [NROWS] row logsumexp
constexpr size_t OFF_A   = (size_t)NROWS;            // [NROWS] scaling a
constexpr size_t OFF_B0  = 2 * (size_t)NROWS;        // [KPAD]  b ping
constexpr size_t OFF_B1  = OFF_B0 + KPAD;            // [KPAD]  b pong
constexpr size_t OFF_BF  = OFF_B0 + 2 * KPAD;        // [KPAD]  b final
constexpr size_t OFF_EP  = OFF_B0 + 3 * KPAD;        // [KPAD]  per-col diff^2
constexpr size_t OFF_CP  = OFF_B0 + 4 * KPAD;        // [BLOCKS*KP1] col partials

__device__ __forceinline__ float waveReduceSum(float v) {
#pragma unroll
  for (int s = 32; s >= 1; s >>= 1) v += __shfl_xor(v, s);
  return v;
}
__device__ __forceinline__ float waveReduceMax(float v) {
#pragma unroll
  for (int s = 32; s >= 1; s >>= 1) v = fmaxf(v, __shfl_xor(v, s));
  return v;
}

// ---------------------------------------------------------------------------
// Kernel 1: per-row logsumexp (stable), plus init of b0 = 1/(k+1).
// One wave per row; lane l holds cols [4l..4l+3] and [256+4l..256+4l+3].
// ---------------------------------------------------------------------------
__global__ __launch_bounds__(1024) void lse_init_kernel(
    const float* __restrict__ logits, float* __restrict__ ws) {
  float* lse = ws + OFF_LSE;
  const int nw   = (gridDim.x * blockDim.x) >> 6;
  const int gw   = (blockIdx.x * blockDim.x + threadIdx.x) >> 6;
  const int lane = threadIdx.x & 63;

  for (int r = gw; r < NROWS; r += nw) {
    const float4* row4 = reinterpret_cast<const float4*>(logits + (size_t)r * KCOLS);
    float4 x0 = row4[lane];
    float4 x1 = row4[64 + lane];
    float m = fmaxf(fmaxf(fmaxf(x0.x, x0.y), fmaxf(x0.z, x0.w)),
                    fmaxf(fmaxf(x1.x, x1.y), fmaxf(x1.z, x1.w)));
    m = waveReduceMax(m);
    float s = exp2f((x0.x - m) * LOG2E) + exp2f((x0.y - m) * LOG2E)
            + exp2f((x0.z - m) * LOG2E) + exp2f((x0.w - m) * LOG2E)
            + exp2f((x1.x - m) * LOG2E) + exp2f((x1.y - m) * LOG2E)
            + exp2f((x1.z - m) * LOG2E) + exp2f((x1.w - m) * LOG2E);
    s = waveReduceSum(s);
    if (lane == 0) lse[r] = m + log2f(s) * LN2;
  }
  if (blockIdx.x == 0 && threadIdx.x < KP1)
    ws[OFF_B0 + threadIdx.x] = 1.0f / 513.0f;
}

// ---------------------------------------------------------------------------
// Kernel 2 (cooperative): the whole Sinkhorn while-loop.
// Phase A (rows): fused a-update + column-partial accumulation (one pass over
//                 the matrix, Q recomputed on the fly from logits+lse).
// Phase B (cols): reduce partials -> b update + per-column diff^2.
// err reduced with an identical fixed-order reduction in every block so the
// break decision is bit-identical grid-wide (no divergent grid.sync).
// ---------------------------------------------------------------------------
__global__ __launch_bounds__(THREADS, 1) void sinkhorn_loop(
    const float* __restrict__ logits, float* __restrict__ ws) {
  float* lse  = ws + OFF_LSE;
  float* a    = ws + OFF_A;
  float* b0   = ws + OFF_B0;
  float* b1   = ws + OFF_B1;
  float* bfin = ws + OFF_BF;
  float* ep   = ws + OFF_EP;
  float* colp = ws + OFF_CP;

  cg::grid_group grid = cg::this_grid();
  __shared__ float lds[WPB][KP1];   // 16*513*4 = 32,832 B
  __shared__ float s_err;

  const int tid  = threadIdx.x;
  const int wv   = tid >> 6;
  const int lane = tid & 63;
  const int gw   = blockIdx.x * WPB + wv;   // global wave id [0, 4096)

  float err = 1.0f;
  int it = 0;
  for (; it < MAXIT; ++it) {
    // while (err > STOPERR && it < MAXIT)  -- NaN err also stops (matches JAX)
    if (!(err > STOPERR)) break;

    const float* bc = (it & 1) ? b1 : b0;
    float*       bn = (it & 1) ? b0 : b1;

    // stage current b into registers (per-lane fixed columns)
    const float4* bc4 = reinterpret_cast<const float4*>(bc);
    float4 rb0 = bc4[lane];
    float4 rb1 = bc4[64 + lane];
    float  bdum = bc[512];

    // ---- phase A: rows ----
    float cp0 = 0.f, cp1 = 0.f, cp2 = 0.f, cp3 = 0.f;
    float cp4 = 0.f, cp5 = 0.f, cp6 = 0.f, cp7 = 0.f;
    float adum = 0.f;
    for (int r = gw; r < NROWS; r += NWAVES) {
      const float4* row4 = reinterpret_cast<const float4*>(logits + (size_t)r * KCOLS);
      float4 x0 = row4[lane];
      float4 x1 = row4[64 + lane];
      float  L  = lse[r];
      float q0 = exp2f((x0.x - L) * CQ);
      float q1 = exp2f((x0.y - L) * CQ);
      float q2 = exp2f((x0.z - L) * CQ);
      float q3 = exp2f((x0.w - L) * CQ);
      float q4 = exp2f((x1.x - L) * CQ);
      float q5 = exp2f((x1.y - L) * CQ);
      float q6 = exp2f((x1.z - L) * CQ);
      float q7 = exp2f((x1.w - L) * CQ);
      float dot = q0 * rb0.x + q1 * rb0.y + q2 * rb0.z + q3 * rb0.w
                + q4 * rb1.x + q5 * rb1.y + q6 * rb1.z + q7 * rb1.w;
      dot = waveReduceSum(dot) + bdum;     // + dummy column (Q=1)
      float ai = PA / dot;
      if (lane == 0) a[r] = ai;
      cp0 += ai * q0;  cp1 += ai * q1;  cp2 += ai * q2;  cp3 += ai * q3;
      cp4 += ai * q4;  cp5 += ai * q5;  cp6 += ai * q6;  cp7 += ai * q7;
      adum += ai;
    }
    // combine 16 waves' column partials via LDS -> one partial row per block
    lds[wv][4 * lane + 0] = cp0;
    lds[wv][4 * lane + 1] = cp1;
    lds[wv][4 * lane + 2] = cp2;
    lds[wv][4 * lane + 3] = cp3;
    lds[wv][256 + 4 * lane + 0] = cp4;
    lds[wv][256 + 4 * lane + 1] = cp5;
    lds[wv][256 + 4 * lane + 2] = cp6;
    lds[wv][256 + 4 * lane + 3] = cp7;
    if (lane == 0) lds[wv][512] = adum;
    __syncthreads();
    for (int t = tid; t < KP1; t += THREADS) {
      float s = 0.f;
#pragma unroll
      for (int w2 = 0; w2 < WPB; ++w2) s += lds[w2][t];
      colp[(size_t)blockIdx.x * KP1 + t] = s;
    }
    grid.sync();

    // ---- phase B: columns (waves 0..512, one column each) ----
    if (gw < KP1) {
      const int j = gw;
      float s = 0.f;
#pragma unroll
      for (int w2 = lane; w2 < BLOCKS; w2 += 64) s += colp[(size_t)w2 * KP1 + j];
      s = waveReduceSum(s);
      if (lane == 0) {
        float bj = (j < KCOLS) ? powf(PB_REAL / s, FI) : (PB_DUM / s);
        bn[j] = bj;
        float d = bj - bc[j];
        ep[j] = d * d;
      }
    }
    grid.sync();

    // ---- err: identical fixed-order reduction in every block ----
    if (wv == 0) {
      float s = 0.f;
      for (int t = lane; t < KP1; t += 64) s += ep[t];
      s = waveReduceSum(s);
      if (lane == 0) s_err = sqrtf(s);
    }
    __syncthreads();
    err = s_err;
  }

  // publish final b (bodies executed = it; last write went to buf[it&1])
  if (blockIdx.x == 0) {
    const float* bf = (it & 1) ? b1 : b0;
    for (int t = tid; t < KP1; t += THREADS) bfin[t] = bf[t];
  }
}

// ---------------------------------------------------------------------------
// Kernel 3: plan = n * a * Q * b^T, drop dummy column, write f32 [NROWS, KCOLS]
// ---------------------------------------------------------------------------
__global__ __launch_bounds__(1024) void plan_epilogue(
    const float* __restrict__ logits, const float* __restrict__ ws,
    float* __restrict__ out) {
  const float* lse  = ws + OFF_LSE;
  const float* a    = ws + OFF_A;
  const float* bfin = ws + OFF_BF;
  const int nw   = (gridDim.x * blockDim.x) >> 6;
  const int gw   = (blockIdx.x * blockDim.x + threadIdx.x) >> 6;
  const int lane = threadIdx.x & 63;

  const float4* b4 = reinterpret_cast<const float4*>(bfin);
  float4 rb0 = b4[lane];
  float4 rb1 = b4[64 + lane];

  for (int r = gw; r < NROWS; r += nw) {
    const float4* row4 = reinterpret_cast<const float4*>(logits + (size_t)r * KCOLS);
    float4*       out4 = reinterpret_cast<float4*>(out + (size_t)r * KCOLS);
    float L  = lse[r];
    float na = a[r] * (float)NROWS;   // n * a_i
    float4 x0 = row4[lane];
    float4 x1 = row4[64 + lane];
    float4 o0, o1;
    o0.x = na * exp2f((x0.x - L) * CQ) * rb0.x;
    o0.y = na * exp2f((x0.y - L) * CQ) * rb0.y;
    o0.z = na * exp2f((x0.z - L) * CQ) * rb0.z;
    o0.w = na * exp2f((x0.w - L) * CQ) * rb0.w;
    o1.x = na * exp2f((x1.x - L) * CQ) * rb1.x;
    o1.y = na * exp2f((x1.y - L) * CQ) * rb1.y;
    o1.z = na * exp2f((x1.z - L) * CQ) * rb1.z;
    o1.w = na * exp2f((x1.w - L) * CQ) * rb1.w;
    out4[lane]      = o0;
    out4[64 + lane] = o1;
  }
}

extern "C" void kernel_launch(void* const* d_in, const int* in_sizes, int n_in,
                              void* d_out, int out_size, void* d_ws, size_t ws_size,
                              hipStream_t stream) {
  (void)in_sizes; (void)n_in; (void)out_size; (void)ws_size;
  const float* logits = (const float*)d_in[0];
  float*       out    = (float*)d_out;
  float*       ws     = (float*)d_ws;   // needs ~1.6 MB

  hipLaunchKernelGGL(lse_init_kernel, dim3(1024), dim3(1024), 0, stream,
                     logits, ws);

  const float* lgArg = logits;
  float*       wsArg = ws;
  void* args[] = { (void*)&lgArg, (void*)&wsArg };
  hipLaunchCooperativeKernel((void*)sinkhorn_loop, dim3(BLOCKS), dim3(THREADS),
                             args, 0, stream);

  hipLaunchKernelGGL(plan_epilogue, dim3(2048), dim3(1024), 0, stream,
                     logits, ws, out);
}